// Round 8
// baseline (666.491 us; speedup 1.0000x reference)
//
#include <hip/hip_runtime.h>
#include <stdint.h>

#define NTOK 4096      // B*S tokens
#define DMODEL 1024
#define FF 4096
#define NEXP 8

typedef __bf16 bf16x8 __attribute__((ext_vector_type(8)));
typedef float f32x4 __attribute__((ext_vector_type(4)));
typedef unsigned short u16x8 __attribute__((ext_vector_type(8)));

__device__ __forceinline__ unsigned short f2bf(float f) {
  union { float f; unsigned u; } v; v.f = f;
  unsigned r = v.u + 0x7fffu + ((v.u >> 16) & 1u);   // RNE
  return (unsigned short)(r >> 16);
}

// ---------------- fp32 -> bf16 straight convert (x) ----------------
__global__ __launch_bounds__(256) void k_convert_x(const float4* __restrict__ in,
                                                   ushort4* __restrict__ out, int n4) {
  int stride = gridDim.x * blockDim.x;
  for (int i = blockIdx.x * blockDim.x + threadIdx.x; i < n4; i += stride) {
    float4 v = in[i];
    out[i] = make_ushort4(f2bf(v.x), f2bf(v.y), f2bf(v.z), f2bf(v.w));
  }
}

// ------- per-expert transpose+convert: in [R][C] fp32 -> out [C][R] bf16 -------
// (measured ~BW-bound; unchanged from round 7)
__global__ __launch_bounds__(256) void k_transpose_bf16(const float* __restrict__ in,
                                                        unsigned short* __restrict__ out,
                                                        int R, int C) {
  __shared__ float tile[64][65];
  const size_t slab = (size_t)R * C;
  const float* ip = in + slab * blockIdx.z;
  unsigned short* op = out + slab * blockIdx.z;
  int c0 = blockIdx.x * 64, r0 = blockIdx.y * 64;
  int tx = threadIdx.x & 15, ty = threadIdx.x >> 4;
#pragma unroll
  for (int i = 0; i < 4; ++i) {
    int r = ty + 16 * i;
    float4 v = *(const float4*)(ip + (size_t)(r0 + r) * C + c0 + tx * 4);
    tile[r][tx * 4 + 0] = v.x;
    tile[r][tx * 4 + 1] = v.y;
    tile[r][tx * 4 + 2] = v.z;
    tile[r][tx * 4 + 3] = v.w;
  }
  __syncthreads();
  int w = threadIdx.x >> 6, lane = threadIdx.x & 63;
  int rc = (lane & 7) * 8;
#pragma unroll
  for (int pass = 0; pass < 2; ++pass) {
    int c = pass * 32 + w * 8 + (lane >> 3);
    u16x8 o;
#pragma unroll
    for (int j = 0; j < 8; ++j) o[j] = f2bf(tile[rc + j][c]);
    *(u16x8*)(op + (size_t)(c0 + c) * R + r0 + rc) = o;
  }
}

// ---------------- router: logits -> top2 -> softmax-over-2 + expert lists ----------------
__global__ __launch_bounds__(256) void k_router(const float* __restrict__ x,
                                                const float* __restrict__ wg,
                                                int* __restrict__ cnt,
                                                int* __restrict__ elist,
                                                float* __restrict__ gw) {
  int wave = threadIdx.x >> 6, lane = threadIdx.x & 63;
  int t = blockIdx.x * 4 + wave;
  const float* xp = x + (size_t)t * DMODEL;
  float a[8] = {0, 0, 0, 0, 0, 0, 0, 0};
#pragma unroll
  for (int i = 0; i < DMODEL / 64; ++i) {
    int d = lane + 64 * i;
    float xv = xp[d];
    float4 w0 = *(const float4*)(wg + d * 8);
    float4 w1 = *(const float4*)(wg + d * 8 + 4);
    a[0] += xv * w0.x; a[1] += xv * w0.y; a[2] += xv * w0.z; a[3] += xv * w0.w;
    a[4] += xv * w1.x; a[5] += xv * w1.y; a[6] += xv * w1.z; a[7] += xv * w1.w;
  }
#pragma unroll
  for (int off = 32; off > 0; off >>= 1)
#pragma unroll
    for (int e = 0; e < 8; ++e) a[e] += __shfl_down(a[e], off, 64);
  if (lane == 0) {
    int e0 = 0;
    for (int e = 1; e < 8; ++e) if (a[e] > a[e0]) e0 = e;          // strict >: lowest idx wins ties (lax.top_k)
    int e1 = (e0 == 0) ? 1 : 0;
    for (int e = 0; e < 8; ++e) if (e != e0 && a[e] > a[e1]) e1 = e;
    float p = __expf(a[e1] - a[e0]);                                // <= 1
    float inv = 1.0f / (1.0f + p);
    int p0 = atomicAdd(&cnt[e0], 1);
    elist[e0 * NTOK + p0] = 2 * t;
    gw[2 * t] = inv;
    int p1 = atomicAdd(&cnt[e1], 1);
    elist[e1 * NTOK + p1] = 2 * t + 1;
    gw[2 * t + 1] = p * inv;
  }
}

// ---------------- GEMM1: gathered x @ w_gate_up, in-register SwiGLU -> act bf16 ----------------
// Round-3 schedule (best measured). Grid flattened 1D with XCD-chunked remap (T1):
// orig = (bid&7)*512 + bid>>3; g = orig>>4 (= e*32 + xcol), y = orig&15.
// -> XCD k runs exactly expert k; within an XCD, the 16 y-blocks of each column-group are
// consecutive -> weight slice (0.5MB) L2-hot; staging drain waits on L2 not HBM latency.
__global__ __launch_bounds__(512, 2) void k_gemm1(const unsigned short* __restrict__ xb,  // [NTOK][D]
                                                  const unsigned short* __restrict__ wgu, // [E][2F][D] bf16
                                                  const int* __restrict__ cnt,
                                                  const int* __restrict__ elist,
                                                  unsigned short* __restrict__ act)       // [2*NTOK][FF]
{
  __shared__ __align__(16) unsigned short sA[2][256 * 64];   // 64KB
  __shared__ __align__(16) unsigned short sB[2][256 * 64];   // 64KB

  const int bid = blockIdx.x;
  const int orig = (bid & 7) * 512 + (bid >> 3);       // bijective on [0,4096)
  const int g = orig >> 4;                             // e*32 + xcol
  const int y = orig & 15;
  const int e = g >> 5;
  const int n_e = cnt[e];
  const int m0 = y * 256;
  if (m0 >= n_e) return;
  const int c0 = (g & 31) * 128;                       // act column base
  const int tid = threadIdx.x;
  const int w = tid >> 6, lane = tid & 63;
  const int wr = w >> 2, wc = w & 3;
  const int* el = elist + e * NTOK;
  const int csub = ((lane & 7) ^ (lane >> 3)) * 8;     // pre-swizzled global k chunk (shorts)
  const int srow = w * 8 + (lane >> 3);                // staging row within each 64-row group

  int tokrow[4];
  size_t baddr[4];
  const unsigned short* wb = wgu + (size_t)e * (2 * FF) * DMODEL;
#pragma unroll
  for (int i = 0; i < 4; ++i) {
    int r = i * 64 + srow;                             // LDS row 0..255
    int idx = m0 + r;
    tokrow[i] = el[idx < n_e ? idx : 0] >> 1;
    int strip = r >> 6, off = r & 63;
    int wrow = (off < 32) ? (c0 + strip * 32 + off) : (FF + c0 + strip * 32 + off - 32);
    baddr[i] = (size_t)wrow * DMODEL;
  }

  f32x4 acc[8][4];
  f32x4 zero = {0.f, 0.f, 0.f, 0.f};
#pragma unroll
  for (int m = 0; m < 8; ++m)
#pragma unroll
    for (int n = 0; n < 4; ++n) acc[m][n] = zero;

  auto stage = [&](int buf, int k0) {
#pragma unroll
    for (int i = 0; i < 4; ++i) {
      const unsigned short* g2 = xb + (size_t)tokrow[i] * DMODEL + k0 + csub;
      __builtin_amdgcn_global_load_lds((const __attribute__((address_space(1))) void*)g2,
                                       (__attribute__((address_space(3))) void*)(&sA[buf][(i * 64 + w * 8) * 64]),
                                       16, 0, 0);
    }
#pragma unroll
    for (int i = 0; i < 4; ++i) {
      const unsigned short* g2 = wb + baddr[i] + k0 + csub;
      __builtin_amdgcn_global_load_lds((const __attribute__((address_space(1))) void*)g2,
                                       (__attribute__((address_space(3))) void*)(&sB[buf][(i * 64 + w * 8) * 64]),
                                       16, 0, 0);
    }
  };

  auto compute = [&](int buf) {
#pragma unroll
    for (int kk = 0; kk < 2; ++kk) {
      const int xk = ((kk * 4 + (lane >> 4)) ^ (lane & 7)) * 8;   // swizzled chunk (shorts)
      bf16x8 af[8], bf[4];
#pragma unroll
      for (int m = 0; m < 8; ++m)
        af[m] = *(const bf16x8*)(&sA[buf][(wr * 128 + m * 16 + (lane & 15)) * 64 + xk]);
#pragma unroll
      for (int n = 0; n < 4; ++n)
        bf[n] = *(const bf16x8*)(&sB[buf][(wc * 64 + n * 16 + (lane & 15)) * 64 + xk]);
#pragma unroll
      for (int m = 0; m < 8; ++m)
#pragma unroll
        for (int n = 0; n < 4; ++n)
          acc[m][n] = __builtin_amdgcn_mfma_f32_16x16x32_bf16(af[m], bf[n], acc[m][n], 0, 0, 0);
    }
  };

  stage(0, 0);
  __syncthreads();                                     // drains prologue stage (vmcnt0) + barrier
  int cur = 0;
  for (int t = 0; t < DMODEL / 64; ++t) {
    if (t + 1 < DMODEL / 64) stage(cur ^ 1, (t + 1) * 64);  // prefetch overlaps MFMAs below
    compute(cur);
    __syncthreads();                                   // vmcnt(0)+lgkmcnt(0)+barrier: next buf ready
    cur ^= 1;
  }

  // ---- in-register SwiGLU: g = acc[m][0/1], u = acc[m][2/3] (same cols), store bf16 ----
#pragma unroll
  for (int m = 0; m < 8; ++m) {
#pragma unroll
    for (int r = 0; r < 4; ++r) {
      int idx = m0 + wr * 128 + m * 16 + (lane >> 4) * 4 + r;
      if (idx < n_e) {
        int p = el[idx];
        unsigned short* ap = act + (size_t)p * FF + c0 + wc * 32;
#pragma unroll
        for (int n = 0; n < 2; ++n) {
          float gv = acc[m][n][r];
          float u = acc[m][n + 2][r];
          float s = gv / (1.0f + __expf(-gv));         // silu
          ap[n * 16 + (lane & 15)] = f2bf(s * u);
        }
      }
    }
  }
}

// ============ GEMM2: gathered act @ w_down, gate-scaled -> out_slot fp32 ============
// m97 structure (kept) + XCD-chunked 1D grid (T1): orig = (bid&7)*256 + bid>>3;
// g = orig>>5 (= e*8 + xcol), y = orig&31. XCD k runs expert k only; the 32 y-blocks of
// each (e,xcol) are consecutive on one XCD -> 1MB weight slice fetched once into L2
// instead of ~8x across XCDs. Predicted: FETCH ~300-500MB -> ~150MB.
__global__ __launch_bounds__(256, 4) void k_gemm2(const unsigned short* __restrict__ actb, // [2*NTOK][FF]
                                                  const unsigned short* __restrict__ wd,   // [E][D][FF] bf16
                                                  const int* __restrict__ cnt,
                                                  const int* __restrict__ elist,
                                                  const float* __restrict__ gw,
                                                  float* __restrict__ out_slot)            // [2*NTOK][D]
{
  __shared__ __align__(16) unsigned short sA[128 * 64];   // 16KB
  __shared__ __align__(16) unsigned short sB[128 * 64];   // 16KB

  const int bid = blockIdx.x;
  const int orig = (bid & 7) * 256 + (bid >> 3);       // bijective on [0,2048)
  const int g = orig >> 5;                             // e*8 + xcol
  const int y = orig & 31;
  const int e = g >> 3;
  const int n_e = cnt[e];
  const int m0 = y * 128;
  if (m0 >= n_e) return;
  const int n0 = (g & 7) * 128;
  const int tid = threadIdx.x;
  const int w = tid >> 6, lane = tid & 63;
  const int wr = w >> 1, wc = w & 1;
  const int* el = elist + e * NTOK;
  const int csub = ((lane & 7) ^ (lane >> 3)) * 8;     // pre-swizzled global k chunk (shorts)

  int prow[4];
  size_t baddr[4];
  const unsigned short* wb = wd + (size_t)e * DMODEL * FF;
#pragma unroll
  for (int i = 0; i < 4; ++i) {
    int r = i * 32 + w * 8 + (lane >> 3);              // staging row 0..127
    int idx = m0 + r;
    prow[i] = el[idx < n_e ? idx : 0];
    baddr[i] = (size_t)(n0 + r) * FF;
  }

  f32x4 acc[4][4];
  f32x4 zero = {0.f, 0.f, 0.f, 0.f};
#pragma unroll
  for (int m = 0; m < 4; ++m)
#pragma unroll
    for (int n = 0; n < 4; ++n) acc[m][n] = zero;

  for (int k0 = 0; k0 < FF; k0 += 64) {
#pragma unroll
    for (int i = 0; i < 4; ++i) {
      const unsigned short* g2 = actb + (size_t)prow[i] * FF + k0 + csub;
      __builtin_amdgcn_global_load_lds((const __attribute__((address_space(1))) void*)g2,
                                       (__attribute__((address_space(3))) void*)(&sA[(i * 32 + w * 8) * 64]),
                                       16, 0, 0);
    }
#pragma unroll
    for (int i = 0; i < 4; ++i) {
      const unsigned short* g2 = wb + baddr[i] + k0 + csub;
      __builtin_amdgcn_global_load_lds((const __attribute__((address_space(1))) void*)g2,
                                       (__attribute__((address_space(3))) void*)(&sB[(i * 32 + w * 8) * 64]),
                                       16, 0, 0);
    }
    __syncthreads();                                   // vmcnt(0) drain + barrier: tile ready
#pragma unroll
    for (int kk = 0; kk < 2; ++kk) {
      const int xk = ((kk * 4 + (lane >> 4)) ^ (lane & 7)) * 8;   // swizzled chunk (shorts)
      bf16x8 af[4], bf[4];
#pragma unroll
      for (int m = 0; m < 4; ++m)
        af[m] = *(const bf16x8*)(&sA[(wr * 64 + m * 16 + (lane & 15)) * 64 + xk]);
#pragma unroll
      for (int n = 0; n < 4; ++n)
        bf[n] = *(const bf16x8*)(&sB[(wc * 64 + n * 16 + (lane & 15)) * 64 + xk]);
#pragma unroll
      for (int m = 0; m < 4; ++m)
#pragma unroll
        for (int n = 0; n < 4; ++n)
          acc[m][n] = __builtin_amdgcn_mfma_f32_16x16x32_bf16(af[m], bf[n], acc[m][n], 0, 0, 0);
    }
    __syncthreads();                                   // protect LDS from next stage
  }

#pragma unroll
  for (int m = 0; m < 4; ++m) {
#pragma unroll
    for (int r = 0; r < 4; ++r) {
      int idx = m0 + wr * 64 + m * 16 + (lane >> 4) * 4 + r;
      if (idx < n_e) {
        int p = el[idx];
        float wgt = gw[p];
        float* op = out_slot + (size_t)p * DMODEL + n0 + wc * 64;
#pragma unroll
        for (int n = 0; n < 4; ++n)
          op[n * 16 + (lane & 15)] = acc[m][n][r] * wgt;
      }
    }
  }
}

// ---------------- combine the two slots per token ----------------
__global__ __launch_bounds__(256) void k_combine(const float4* __restrict__ slot,
                                                 float4* __restrict__ out, int n4) {
  int stride = gridDim.x * blockDim.x;
  for (int i = blockIdx.x * blockDim.x + threadIdx.x; i < n4; i += stride) {
    int t = i >> 8;               // DMODEL/4 = 256 float4 per row
    int j = i & 255;
    float4 a = slot[(size_t)(2 * t) * 256 + j];
    float4 b = slot[(size_t)(2 * t + 1) * 256 + j];
    float4 o;
    o.x = a.x + b.x; o.y = a.y + b.y; o.z = a.z + b.z; o.w = a.w + b.w;
    out[i] = o;
  }
}

extern "C" void kernel_launch(void* const* d_in, const int* in_sizes, int n_in,
                              void* d_out, int out_size, void* d_ws, size_t ws_size,
                              hipStream_t stream) {
  const float* x   = (const float*)d_in[0];
  const float* wg  = (const float*)d_in[1];
  const float* wgu = (const float*)d_in[2];
  const float* wd  = (const float*)d_in[3];
  float* out = (float*)d_out;

  char* ws = (char*)d_ws;
  size_t off = 0;
  auto alloc = [&](size_t bytes) -> char* {
    char* p = ws + off;
    off += (bytes + 255) & ~(size_t)255;
    return p;
  };
  unsigned short* wgu_t = (unsigned short*)alloc((size_t)NEXP * 2 * FF * DMODEL * 2); // 134MB [E][2F][D]
  unsigned short* wd_t  = (unsigned short*)alloc((size_t)NEXP * DMODEL * FF * 2);     // 67MB  [E][D][F]
  unsigned short* actb  = (unsigned short*)alloc((size_t)2 * NTOK * FF * 2);          // 67MB
  float* out_slot       = (float*)alloc((size_t)2 * NTOK * DMODEL * 4);               // 33.5MB
  unsigned short* xb    = (unsigned short*)alloc((size_t)NTOK * DMODEL * 2);          // 8.4MB
  int* elist            = (int*)alloc((size_t)NEXP * NTOK * 4);
  float* gw             = (float*)alloc((size_t)2 * NTOK * 4);
  int* cnt              = (int*)alloc(256);
  if (off > ws_size) return;  // workspace too small -> leave output poisoned (clear failure signal)

  hipMemsetAsync(cnt, 0, 256, stream);
  k_convert_x<<<1024, 256, 0, stream>>>((const float4*)x, (ushort4*)xb, NTOK * DMODEL / 4);
  k_transpose_bf16<<<dim3(2 * FF / 64, DMODEL / 64, NEXP), 256, 0, stream>>>(wgu, wgu_t, DMODEL, 2 * FF);
  k_transpose_bf16<<<dim3(DMODEL / 64, FF / 64, NEXP), 256, 0, stream>>>(wd, wd_t, FF, DMODEL);
  k_router<<<NTOK / 4, 256, 0, stream>>>(x, wg, cnt, elist, gw);
  k_gemm1<<<4096, 512, 0, stream>>>(xb, wgu_t, cnt, elist, actb);
  k_gemm2<<<2048, 256, 0, stream>>>(actb, wd_t, cnt, elist, gw, out_slot);
  k_combine<<<2048, 256, 0, stream>>>((const float4*)out_slot, (float4*)out, NTOK * DMODEL / 4);
}

// Round 9
// 564.523 us; speedup vs baseline: 1.1806x; 1.1806x over previous
//
#include <hip/hip_runtime.h>
#include <stdint.h>

#define NTOK 4096      // B*S tokens
#define DMODEL 1024
#define FF 4096
#define NEXP 8

typedef __bf16 bf16x8 __attribute__((ext_vector_type(8)));
typedef float f32x4 __attribute__((ext_vector_type(4)));
typedef unsigned short u16x8 __attribute__((ext_vector_type(8)));

__device__ __forceinline__ unsigned short f2bf(float f) {
  union { float f; unsigned u; } v; v.f = f;
  unsigned r = v.u + 0x7fffu + ((v.u >> 16) & 1u);   // RNE
  return (unsigned short)(r >> 16);
}

// ---------------- fp32 -> bf16 straight convert (x) ----------------
__global__ __launch_bounds__(256) void k_convert_x(const float4* __restrict__ in,
                                                   ushort4* __restrict__ out, int n4) {
  int stride = gridDim.x * blockDim.x;
  for (int i = blockIdx.x * blockDim.x + threadIdx.x; i < n4; i += stride) {
    float4 v = in[i];
    out[i] = make_ushort4(f2bf(v.x), f2bf(v.y), f2bf(v.z), f2bf(v.w));
  }
}

// ------- per-expert transpose+convert: in [R][C] fp32 -> out [C][R] bf16 -------
// (measured ~BW-bound; unchanged)
__global__ __launch_bounds__(256) void k_transpose_bf16(const float* __restrict__ in,
                                                        unsigned short* __restrict__ out,
                                                        int R, int C) {
  __shared__ float tile[64][65];
  const size_t slab = (size_t)R * C;
  const float* ip = in + slab * blockIdx.z;
  unsigned short* op = out + slab * blockIdx.z;
  int c0 = blockIdx.x * 64, r0 = blockIdx.y * 64;
  int tx = threadIdx.x & 15, ty = threadIdx.x >> 4;
#pragma unroll
  for (int i = 0; i < 4; ++i) {
    int r = ty + 16 * i;
    float4 v = *(const float4*)(ip + (size_t)(r0 + r) * C + c0 + tx * 4);
    tile[r][tx * 4 + 0] = v.x;
    tile[r][tx * 4 + 1] = v.y;
    tile[r][tx * 4 + 2] = v.z;
    tile[r][tx * 4 + 3] = v.w;
  }
  __syncthreads();
  int w = threadIdx.x >> 6, lane = threadIdx.x & 63;
  int rc = (lane & 7) * 8;
#pragma unroll
  for (int pass = 0; pass < 2; ++pass) {
    int c = pass * 32 + w * 8 + (lane >> 3);
    u16x8 o;
#pragma unroll
    for (int j = 0; j < 8; ++j) o[j] = f2bf(tile[rc + j][c]);
    *(u16x8*)(op + (size_t)(c0 + c) * R + r0 + rc) = o;
  }
}

// ---------------- router: logits -> top2 -> softmax-over-2 + expert lists ----------------
__global__ __launch_bounds__(256) void k_router(const float* __restrict__ x,
                                                const float* __restrict__ wg,
                                                int* __restrict__ cnt,
                                                int* __restrict__ elist,
                                                float* __restrict__ gw) {
  int wave = threadIdx.x >> 6, lane = threadIdx.x & 63;
  int t = blockIdx.x * 4 + wave;
  const float* xp = x + (size_t)t * DMODEL;
  float a[8] = {0, 0, 0, 0, 0, 0, 0, 0};
#pragma unroll
  for (int i = 0; i < DMODEL / 64; ++i) {
    int d = lane + 64 * i;
    float xv = xp[d];
    float4 w0 = *(const float4*)(wg + d * 8);
    float4 w1 = *(const float4*)(wg + d * 8 + 4);
    a[0] += xv * w0.x; a[1] += xv * w0.y; a[2] += xv * w0.z; a[3] += xv * w0.w;
    a[4] += xv * w1.x; a[5] += xv * w1.y; a[6] += xv * w1.z; a[7] += xv * w1.w;
  }
#pragma unroll
  for (int off = 32; off > 0; off >>= 1)
#pragma unroll
    for (int e = 0; e < 8; ++e) a[e] += __shfl_down(a[e], off, 64);
  if (lane == 0) {
    int e0 = 0;
    for (int e = 1; e < 8; ++e) if (a[e] > a[e0]) e0 = e;          // strict >: lowest idx wins ties (lax.top_k)
    int e1 = (e0 == 0) ? 1 : 0;
    for (int e = 0; e < 8; ++e) if (e != e0 && a[e] > a[e1]) e1 = e;
    float p = __expf(a[e1] - a[e0]);                                // <= 1
    float inv = 1.0f / (1.0f + p);
    int p0 = atomicAdd(&cnt[e0], 1);
    elist[e0 * NTOK + p0] = 2 * t;
    gw[2 * t] = inv;
    int p1 = atomicAdd(&cnt[e1], 1);
    elist[e1 * NTOK + p1] = 2 * t + 1;
    gw[2 * t + 1] = p * inv;
  }
}

// ---------------- GEMM1: gathered x @ w_gate_up, in-register SwiGLU -> act bf16 ----------------
// Round-3 schedule + ORIGINAL 3D grid (measured best 236us). NOTE: this grid already has
// weight L2 locality: bid = x + 32y + 512e -> XCD = x%8, all 16 y-blocks of an (e,x) weight
// slice land on one XCD with reuse distance ~4 blocks (FETCH ~= 1x weights, measured).
// Round-8's expert-per-XCD remap REGRESSED it (tail: critical path = largest expert).
__global__ __launch_bounds__(512, 2) void k_gemm1(const unsigned short* __restrict__ xb,  // [NTOK][D]
                                                  const unsigned short* __restrict__ wgu, // [E][2F][D] bf16
                                                  const int* __restrict__ cnt,
                                                  const int* __restrict__ elist,
                                                  unsigned short* __restrict__ act)       // [2*NTOK][FF]
{
  __shared__ __align__(16) unsigned short sA[2][256 * 64];   // 64KB
  __shared__ __align__(16) unsigned short sB[2][256 * 64];   // 64KB

  const int e = blockIdx.z;
  const int n_e = cnt[e];
  const int m0 = blockIdx.y * 256;
  if (m0 >= n_e) return;
  const int c0 = blockIdx.x * 128;                     // act column base
  const int tid = threadIdx.x;
  const int w = tid >> 6, lane = tid & 63;
  const int wr = w >> 2, wc = w & 3;
  const int* el = elist + e * NTOK;
  const int csub = ((lane & 7) ^ (lane >> 3)) * 8;     // pre-swizzled global k chunk (shorts)
  const int srow = w * 8 + (lane >> 3);                // staging row within each 64-row group

  int tokrow[4];
  size_t baddr[4];
  const unsigned short* wb = wgu + (size_t)e * (2 * FF) * DMODEL;
#pragma unroll
  for (int i = 0; i < 4; ++i) {
    int r = i * 64 + srow;                             // LDS row 0..255
    int idx = m0 + r;
    tokrow[i] = el[idx < n_e ? idx : 0] >> 1;
    int strip = r >> 6, off = r & 63;
    int wrow = (off < 32) ? (c0 + strip * 32 + off) : (FF + c0 + strip * 32 + off - 32);
    baddr[i] = (size_t)wrow * DMODEL;
  }

  f32x4 acc[8][4];
  f32x4 zero = {0.f, 0.f, 0.f, 0.f};
#pragma unroll
  for (int m = 0; m < 8; ++m)
#pragma unroll
    for (int n = 0; n < 4; ++n) acc[m][n] = zero;

  auto stage = [&](int buf, int k0) {
#pragma unroll
    for (int i = 0; i < 4; ++i) {
      const unsigned short* g2 = xb + (size_t)tokrow[i] * DMODEL + k0 + csub;
      __builtin_amdgcn_global_load_lds((const __attribute__((address_space(1))) void*)g2,
                                       (__attribute__((address_space(3))) void*)(&sA[buf][(i * 64 + w * 8) * 64]),
                                       16, 0, 0);
    }
#pragma unroll
    for (int i = 0; i < 4; ++i) {
      const unsigned short* g2 = wb + baddr[i] + k0 + csub;
      __builtin_amdgcn_global_load_lds((const __attribute__((address_space(1))) void*)g2,
                                       (__attribute__((address_space(3))) void*)(&sB[buf][(i * 64 + w * 8) * 64]),
                                       16, 0, 0);
    }
  };

  auto compute = [&](int buf) {
#pragma unroll
    for (int kk = 0; kk < 2; ++kk) {
      const int xk = ((kk * 4 + (lane >> 4)) ^ (lane & 7)) * 8;   // swizzled chunk (shorts)
      bf16x8 af[8], bf[4];
#pragma unroll
      for (int m = 0; m < 8; ++m)
        af[m] = *(const bf16x8*)(&sA[buf][(wr * 128 + m * 16 + (lane & 15)) * 64 + xk]);
#pragma unroll
      for (int n = 0; n < 4; ++n)
        bf[n] = *(const bf16x8*)(&sB[buf][(wc * 64 + n * 16 + (lane & 15)) * 64 + xk]);
#pragma unroll
      for (int m = 0; m < 8; ++m)
#pragma unroll
        for (int n = 0; n < 4; ++n)
          acc[m][n] = __builtin_amdgcn_mfma_f32_16x16x32_bf16(af[m], bf[n], acc[m][n], 0, 0, 0);
    }
  };

  stage(0, 0);
  __syncthreads();                                     // drains prologue stage (vmcnt0) + barrier
  int cur = 0;
  for (int t = 0; t < DMODEL / 64; ++t) {
    if (t + 1 < DMODEL / 64) stage(cur ^ 1, (t + 1) * 64);  // prefetch overlaps MFMAs below
    compute(cur);
    __syncthreads();                                   // vmcnt(0)+lgkmcnt(0)+barrier: next buf ready
    cur ^= 1;
  }

  // ---- in-register SwiGLU: g = acc[m][0/1], u = acc[m][2/3] (same cols), store bf16 ----
#pragma unroll
  for (int m = 0; m < 8; ++m) {
#pragma unroll
    for (int r = 0; r < 4; ++r) {
      int idx = m0 + wr * 128 + m * 16 + (lane >> 4) * 4 + r;
      if (idx < n_e) {
        int p = el[idx];
        unsigned short* ap = act + (size_t)p * FF + c0 + wc * 32;
#pragma unroll
        for (int n = 0; n < 2; ++n) {
          float gv = acc[m][n][r];
          float u = acc[m][n + 2][r];
          float s = gv / (1.0f + __expf(-gv));         // silu
          ap[n * 16 + (lane & 15)] = f2bf(s * u);
        }
      }
    }
  }
}

// ============ GEMM2: gathered act @ w_down, gate-scaled -> out_slot fp32 ============
// m97 structure + XCD-chunked 1D grid (T1, KEPT from round 8 — rest-of-pipeline gained
// ~49us): orig = (bid&7)*256 + bid>>3; g = orig>>5 (= e*8 + xcol), y = orig&31.
// XCD k runs expert k; 1MB weight slice L2-hot instead of 8MB/XCD working set.
// Tail is mild here: 32KB LDS -> 4-5 blocks/CU co-resident.
__global__ __launch_bounds__(256, 4) void k_gemm2(const unsigned short* __restrict__ actb, // [2*NTOK][FF]
                                                  const unsigned short* __restrict__ wd,   // [E][D][FF] bf16
                                                  const int* __restrict__ cnt,
                                                  const int* __restrict__ elist,
                                                  const float* __restrict__ gw,
                                                  float* __restrict__ out_slot)            // [2*NTOK][D]
{
  __shared__ __align__(16) unsigned short sA[128 * 64];   // 16KB
  __shared__ __align__(16) unsigned short sB[128 * 64];   // 16KB

  const int bid = blockIdx.x;
  const int orig = (bid & 7) * 256 + (bid >> 3);       // bijective on [0,2048)
  const int g = orig >> 5;                             // e*8 + xcol
  const int y = orig & 31;
  const int e = g >> 3;
  const int n_e = cnt[e];
  const int m0 = y * 128;
  if (m0 >= n_e) return;
  const int n0 = (g & 7) * 128;
  const int tid = threadIdx.x;
  const int w = tid >> 6, lane = tid & 63;
  const int wr = w >> 1, wc = w & 1;
  const int* el = elist + e * NTOK;
  const int csub = ((lane & 7) ^ (lane >> 3)) * 8;     // pre-swizzled global k chunk (shorts)

  int prow[4];
  size_t baddr[4];
  const unsigned short* wb = wd + (size_t)e * DMODEL * FF;
#pragma unroll
  for (int i = 0; i < 4; ++i) {
    int r = i * 32 + w * 8 + (lane >> 3);              // staging row 0..127
    int idx = m0 + r;
    prow[i] = el[idx < n_e ? idx : 0];
    baddr[i] = (size_t)(n0 + r) * FF;
  }

  f32x4 acc[4][4];
  f32x4 zero = {0.f, 0.f, 0.f, 0.f};
#pragma unroll
  for (int m = 0; m < 4; ++m)
#pragma unroll
    for (int n = 0; n < 4; ++n) acc[m][n] = zero;

  for (int k0 = 0; k0 < FF; k0 += 64) {
#pragma unroll
    for (int i = 0; i < 4; ++i) {
      const unsigned short* g2 = actb + (size_t)prow[i] * FF + k0 + csub;
      __builtin_amdgcn_global_load_lds((const __attribute__((address_space(1))) void*)g2,
                                       (__attribute__((address_space(3))) void*)(&sA[(i * 32 + w * 8) * 64]),
                                       16, 0, 0);
    }
#pragma unroll
    for (int i = 0; i < 4; ++i) {
      const unsigned short* g2 = wb + baddr[i] + k0 + csub;
      __builtin_amdgcn_global_load_lds((const __attribute__((address_space(1))) void*)g2,
                                       (__attribute__((address_space(3))) void*)(&sB[(i * 32 + w * 8) * 64]),
                                       16, 0, 0);
    }
    __syncthreads();                                   // vmcnt(0) drain + barrier: tile ready
#pragma unroll
    for (int kk = 0; kk < 2; ++kk) {
      const int xk = ((kk * 4 + (lane >> 4)) ^ (lane & 7)) * 8;   // swizzled chunk (shorts)
      bf16x8 af[4], bf[4];
#pragma unroll
      for (int m = 0; m < 4; ++m)
        af[m] = *(const bf16x8*)(&sA[(wr * 64 + m * 16 + (lane & 15)) * 64 + xk]);
#pragma unroll
      for (int n = 0; n < 4; ++n)
        bf[n] = *(const bf16x8*)(&sB[(wc * 64 + n * 16 + (lane & 15)) * 64 + xk]);
#pragma unroll
      for (int m = 0; m < 4; ++m)
#pragma unroll
        for (int n = 0; n < 4; ++n)
          acc[m][n] = __builtin_amdgcn_mfma_f32_16x16x32_bf16(af[m], bf[n], acc[m][n], 0, 0, 0);
    }
    __syncthreads();                                   // protect LDS from next stage
  }

#pragma unroll
  for (int m = 0; m < 4; ++m) {
#pragma unroll
    for (int r = 0; r < 4; ++r) {
      int idx = m0 + wr * 64 + m * 16 + (lane >> 4) * 4 + r;
      if (idx < n_e) {
        int p = el[idx];
        float wgt = gw[p];
        float* op = out_slot + (size_t)p * DMODEL + n0 + wc * 64;
#pragma unroll
        for (int n = 0; n < 4; ++n)
          op[n * 16 + (lane & 15)] = acc[m][n][r] * wgt;
      }
    }
  }
}

// ---------------- combine the two slots per token ----------------
__global__ __launch_bounds__(256) void k_combine(const float4* __restrict__ slot,
                                                 float4* __restrict__ out, int n4) {
  int stride = gridDim.x * blockDim.x;
  for (int i = blockIdx.x * blockDim.x + threadIdx.x; i < n4; i += stride) {
    int t = i >> 8;               // DMODEL/4 = 256 float4 per row
    int j = i & 255;
    float4 a = slot[(size_t)(2 * t) * 256 + j];
    float4 b = slot[(size_t)(2 * t + 1) * 256 + j];
    float4 o;
    o.x = a.x + b.x; o.y = a.y + b.y; o.z = a.z + b.z; o.w = a.w + b.w;
    out[i] = o;
  }
}

extern "C" void kernel_launch(void* const* d_in, const int* in_sizes, int n_in,
                              void* d_out, int out_size, void* d_ws, size_t ws_size,
                              hipStream_t stream) {
  const float* x   = (const float*)d_in[0];
  const float* wg  = (const float*)d_in[1];
  const float* wgu = (const float*)d_in[2];
  const float* wd  = (const float*)d_in[3];
  float* out = (float*)d_out;

  char* ws = (char*)d_ws;
  size_t off = 0;
  auto alloc = [&](size_t bytes) -> char* {
    char* p = ws + off;
    off += (bytes + 255) & ~(size_t)255;
    return p;
  };
  unsigned short* wgu_t = (unsigned short*)alloc((size_t)NEXP * 2 * FF * DMODEL * 2); // 134MB [E][2F][D]
  unsigned short* wd_t  = (unsigned short*)alloc((size_t)NEXP * DMODEL * FF * 2);     // 67MB  [E][D][F]
  unsigned short* actb  = (unsigned short*)alloc((size_t)2 * NTOK * FF * 2);          // 67MB
  float* out_slot       = (float*)alloc((size_t)2 * NTOK * DMODEL * 4);               // 33.5MB
  unsigned short* xb    = (unsigned short*)alloc((size_t)NTOK * DMODEL * 2);          // 8.4MB
  int* elist            = (int*)alloc((size_t)NEXP * NTOK * 4);
  float* gw             = (float*)alloc((size_t)2 * NTOK * 4);
  int* cnt              = (int*)alloc(256);
  if (off > ws_size) return;  // workspace too small -> leave output poisoned (clear failure signal)

  hipMemsetAsync(cnt, 0, 256, stream);
  k_convert_x<<<1024, 256, 0, stream>>>((const float4*)x, (ushort4*)xb, NTOK * DMODEL / 4);
  k_transpose_bf16<<<dim3(2 * FF / 64, DMODEL / 64, NEXP), 256, 0, stream>>>(wgu, wgu_t, DMODEL, 2 * FF);
  k_transpose_bf16<<<dim3(DMODEL / 64, FF / 64, NEXP), 256, 0, stream>>>(wd, wd_t, FF, DMODEL);
  k_router<<<NTOK / 4, 256, 0, stream>>>(x, wg, cnt, elist, gw);
  k_gemm1<<<dim3(FF / 128, NTOK / 256, NEXP), 512, 0, stream>>>(xb, wgu_t, cnt, elist, actb);
  k_gemm2<<<2048, 256, 0, stream>>>(actb, wd_t, cnt, elist, gw, out_slot);
  k_combine<<<2048, 256, 0, stream>>>((const float4*)out_slot, (float4*)out, NTOK * DMODEL / 4);
}